// Round 1
// baseline (140.883 us; speedup 1.0000x reference)
//
#include <hip/hip_runtime.h>
#include <stdint.h>

// Rule 110 CA, batch=32, width=16384, 64 iterations, zero boundaries each step.
// idx = L + 2C + 4R, lookup[k]=(110>>k)&1  ==>  new = (L | C) & ~(L & C & R).
//
// v2: replicated-wave fused kernel, no LDS, no barriers.
//   - one trapezoid per (batch row, 1024-cell tile), REPLICATED 4x:
//     grid (16 tiles, 4 replicas, 32 rows) = 2048 single-wave blocks
//     -> 8 waves/CU (vs 2 in v1), pure fire-and-forget streaming stores.
//   - working state = 2048 bits = 1 uint32 per lane, covering [s-64, s+1984);
//     64-cell halo each side absorbs 64 steps of edge staleness
//     (at step t, working bits [t, 2048-t) are exact; tile = bits [64,1088)).
//   - replica z stores only cells [z*256, z*256+256) of the tile each step:
//     one __shfl (ds_bpermute) to fetch the word + one int4 store per lane.
//     CA step itself (2 ballots + ~10 VALU) is recomputed redundantly - cheap.
//   - total writes 512 waves-equivalents x 65 x 4KB = 133 MiB = HBM floor.

#define WIDTH 16384
#define BATCH 32
#define ITERS 64
#define TILE  1024
#define NTILE (WIDTH / TILE)   // 16
#define REP   4                // store-replicas per tile

__global__ __launch_bounds__(64) void ca_fused_kernel(
    const float* __restrict__ x, int* __restrict__ out)
{
    const int lane = threadIdx.x;          // 0..63
    const int tile = blockIdx.x;           // 0..15
    const int z    = blockIdx.y;           // 0..3  replica / store-quarter
    const int b    = blockIdx.z;           // 0..31
    const int s    = tile * TILE;          // output tile start cell

    // ---- pack initial state: lane owns working bits [lane*32, lane*32+32),
    //      i.e. global positions [s-64+lane*32, +32). Boundaries align to lanes.
    const int p0 = s - 64 + lane * 32;
    const bool valid = (p0 >= 0) && (p0 < WIDTH);
    const uint32_t vmask = valid ? 0xffffffffu : 0u;

    uint32_t c = 0;
    if (valid) {
        const float4* xv = (const float4*)(x + (size_t)b * WIDTH + p0);
        #pragma unroll
        for (int i = 0; i < 8; ++i) {
            float4 f = xv[i];
            c |= (uint32_t)(f.x >= 0.5f) << (i * 4 + 0);
            c |= (uint32_t)(f.y >= 0.5f) << (i * 4 + 1);
            c |= (uint32_t)(f.z >= 0.5f) << (i * 4 + 2);
            c |= (uint32_t)(f.w >= 0.5f) << (i * 4 + 3);
        }
    }

    // This replica stores tile cells [z*256 + lane*4, +4) each step.
    // Working bit of first stored cell = 64 + z*256 + lane*4
    //   -> source word  = 2 + z*8 + (lane>>3)   (held by that lane)
    //   -> bit offset   = (lane&7)*4
    const int srcLane = 2 + z * 8 + (lane >> 3);
    const int sh4     = (lane & 7) * 4;

    int* outb = out + ((size_t)b * (ITERS + 1)) * WIDTH + s + z * 256 + lane * 4;

    #pragma unroll 4
    for (int t = 0; t < ITERS; ++t) {
        // ---- store this replica's 256 output cells for step t ----
        uint32_t w   = (uint32_t)__shfl((int)c, srcLane, 64);
        uint32_t nib = w >> sh4;
        *(int4*)outb = make_int4((int)(nib & 1u), (int)((nib >> 1) & 1u),
                                 (int)((nib >> 2) & 1u), (int)((nib >> 3) & 1u));
        outb += WIDTH;

        // ---- one CA step, cross-lane 1-bit carries via 64-bit ballots ----
        uint64_t A  = __ballot((c & 1u) != 0);         // bit l = LSB of lane l
        uint64_t Bm = __ballot((c >> 31) != 0);        // bit l = MSB of lane l
        uint32_t carryL = (uint32_t)(((Bm << 1) >> lane) & 1ull); // MSB of lane-1
        uint32_t carryR = (uint32_t)(((A  >> 1) >> lane) & 1ull); // LSB of lane+1

        uint32_t l = (c << 1) | carryL;
        uint32_t r = (c >> 1) | (carryR << 31);
        c = ((l | c) & ~(l & c & r)) & vmask;  // vmask: out-of-array stays 0
    }

    // ---- final state (t = ITERS) store ----
    uint32_t w   = (uint32_t)__shfl((int)c, srcLane, 64);
    uint32_t nib = w >> sh4;
    *(int4*)outb = make_int4((int)(nib & 1u), (int)((nib >> 1) & 1u),
                             (int)((nib >> 2) & 1u), (int)((nib >> 3) & 1u));
}

extern "C" void kernel_launch(void* const* d_in, const int* in_sizes, int n_in,
                              void* d_out, int out_size, void* d_ws, size_t ws_size,
                              hipStream_t stream)
{
    const float* x = (const float*)d_in[0];
    // d_in[1] = lookup table for rule 110 -- fixed by setup, baked into logic.
    (void)d_ws; (void)ws_size;

    dim3 grid(NTILE, REP, BATCH);   // 16 x 4 x 32 = 2048 single-wave blocks
    ca_fused_kernel<<<grid, 64, 0, stream>>>(x, (int*)d_out);
}

// Round 3
// 140.216 us; speedup vs baseline: 1.0048x; 1.0048x over previous
//
#include <hip/hip_runtime.h>
#include <stdint.h>

// Rule 110 CA, batch=32, width=16384, 64 iterations, zero boundaries each step.
// idx = L + 2C + 4R, lookup[k]=(110>>k)&1  ==>  new = (L | C) & ~(L & C & R).
//
// v3: replicated trapezoid waves + BATCHED STORES for memory-level parallelism.
//   - v1 (LDS bounce, 2 waves/CU) and v2 (no LDS, 8 waves/CU) both ran the CA
//     at ~2.5 TB/s write BW: both keep only ~2 MB of stores in flight chip-wide
//     (v1: 512 waves x 4KB, v2: 2048 waves x 1KB before the register-reuse
//     vmcnt wait). Little's law at ~800ns store latency -> ~2.5 TB/s. MLP-bound.
//   - fix: batch SB=8 steps; snapshot the store word (1 VGPR) each step, then
//     issue 8 back-to-back dwordx4 stores -> ~8KB/wave in flight, 16 MB chip-
//     wide -> write port saturates (~6.5 TB/s, the rocclr fill's rate).
//   - trapezoid halo unchanged (verified in v1/v2): 2048-bit working state,
//     64-cell halo absorbs 64 steps of zero-boundary staleness.
//     Replica z of each (row, tile) stores quarter [z*256, z*256+256).

#define WIDTH 16384
#define BATCH 32
#define ITERS 64
#define TILE  1024
#define NTILE (WIDTH / TILE)   // 16
#define REP   4                // store-replicas per tile
#define SB    8                // steps batched per store burst

__global__ __launch_bounds__(64) void ca_fused_kernel(
    const float* __restrict__ x, int* __restrict__ out)
{
    const int lane = threadIdx.x;          // 0..63
    const int tile = blockIdx.x;           // 0..15
    const int z    = blockIdx.y;           // 0..3  replica / store-quarter
    const int b    = blockIdx.z;           // 0..31
    const int s    = tile * TILE;          // output tile start cell

    // ---- pack initial state: lane owns working bits [lane*32, lane*32+32),
    //      i.e. global positions [s-64+lane*32, +32). Boundaries align to lanes.
    const int p0 = s - 64 + lane * 32;
    const bool valid = (p0 >= 0) && (p0 < WIDTH);
    const uint32_t vmask = valid ? 0xffffffffu : 0u;

    uint32_t c = 0;
    if (valid) {
        const float4* xv = (const float4*)(x + (size_t)b * WIDTH + p0);
        #pragma unroll
        for (int i = 0; i < 8; ++i) {
            float4 f = xv[i];
            c |= (uint32_t)(f.x >= 0.5f) << (i * 4 + 0);
            c |= (uint32_t)(f.y >= 0.5f) << (i * 4 + 1);
            c |= (uint32_t)(f.z >= 0.5f) << (i * 4 + 2);
            c |= (uint32_t)(f.w >= 0.5f) << (i * 4 + 3);
        }
    }

    // This replica stores tile cells [z*256 + lane*4, +4) each step.
    // Working bit of first stored cell = 64 + z*256 + lane*4
    //   -> source word = 2 + z*8 + (lane>>3), bit offset (lane&7)*4
    const int srcLane = 2 + z * 8 + (lane >> 3);
    const int sh4     = (lane & 7) * 4;

    int* outb = out + ((size_t)b * (ITERS + 1)) * WIDTH + s + z * 256 + lane * 4;

    for (int tb = 0; tb < ITERS / SB; ++tb) {
        uint32_t w[SB];   // fully unrolled -> registers (static indices only)

        // ---- compute phase: SB steps, snapshot store-words ----
        #pragma unroll
        for (int u = 0; u < SB; ++u) {
            w[u] = (uint32_t)__shfl((int)c, srcLane, 64);

            uint64_t A  = __ballot((c & 1u) != 0);         // LSBs of all lanes
            uint64_t Bm = __ballot((c >> 31) != 0);        // MSBs of all lanes
            uint32_t carryL = (uint32_t)(((Bm << 1) >> lane) & 1ull);
            uint32_t carryR = (uint32_t)(((A  >> 1) >> lane) & 1ull);

            uint32_t l = (c << 1) | carryL;
            uint32_t r = (c >> 1) | (carryR << 31);
            c = ((l | c) & ~(l & c & r)) & vmask;
        }

        // ---- store phase: SB back-to-back dwordx4 bursts (deep vmcnt) ----
        #pragma unroll
        for (int u = 0; u < SB; ++u) {
            uint32_t nib = w[u] >> sh4;
            *(int4*)(outb + (size_t)u * WIDTH) =
                make_int4((int)(nib & 1u), (int)((nib >> 1) & 1u),
                          (int)((nib >> 2) & 1u), (int)((nib >> 3) & 1u));
        }
        outb += SB * WIDTH;
    }

    // ---- final state (t = ITERS) store ----
    uint32_t wl  = (uint32_t)__shfl((int)c, srcLane, 64);
    uint32_t nib = wl >> sh4;
    *(int4*)outb = make_int4((int)(nib & 1u), (int)((nib >> 1) & 1u),
                             (int)((nib >> 2) & 1u), (int)((nib >> 3) & 1u));
}

extern "C" void kernel_launch(void* const* d_in, const int* in_sizes, int n_in,
                              void* d_out, int out_size, void* d_ws, size_t ws_size,
                              hipStream_t stream)
{
    const float* x = (const float*)d_in[0];
    // d_in[1] = lookup table for rule 110 -- fixed by setup, baked into logic.
    (void)d_ws; (void)ws_size;

    dim3 grid(NTILE, REP, BATCH);   // 16 x 4 x 32 = 2048 single-wave blocks
    ca_fused_kernel<<<grid, 64, 0, stream>>>(x, (int*)d_out);
}